// Round 18
// baseline (402.331 us; speedup 1.0000x reference)
//
#include <hip/hip_runtime.h>
#include <cmath>

#define G_ 128
#define N0_ 512
#define H_ 256
#define E_ 524288
#define NODES0 (G_*N0_)

typedef _Float16 v8h __attribute__((ext_vector_type(8)));
typedef _Float16 v4h __attribute__((ext_vector_type(4)));
typedef float v4f __attribute__((ext_vector_type(4)));

#define TSTRIDE 72           // halfwords per tile row: 32 hi + 32 lo + 8 pad
#define TILEHW (128*TSTRIDE) // 9216 halfwords = 18432 B per tile

__device__ __forceinline__ void async_copy16(void* lds, const void* g) {
  __builtin_amdgcn_global_load_lds(
      (const __attribute__((address_space(1))) void*)g,
      (__attribute__((address_space(3))) void*)lds, 16, 0, 0);
}

// Bijective XCD swizzle (m204 form).
__device__ __forceinline__ int xcd_swizzle(int orig, int nb) {
  int q = nb >> 3, r = nb & 7;
  int xcd = orig & 7, local = orig >> 3;
  int off = (xcd < r) ? xcd * (q + 1) : r * (q + 1) + (xcd - r) * q;
  return off + local;
}

__device__ __forceinline__ float4 f4fma(float4 a, float s, float4 acc) {
  acc.x = fmaf(a.x, s, acc.x); acc.y = fmaf(a.y, s, acc.y);
  acc.z = fmaf(a.z, s, acc.z); acc.w = fmaf(a.w, s, acc.w);
  return acc;
}

// ---------------- setup: pnorm (0-2) + init (3..130) + wconv (131..178) ----------------
__global__ __launch_bounds__(256) void setup_kernel(const float* __restrict__ p0,
                                                    const float* __restrict__ p1,
                                                    const float* __restrict__ p2,
                                                    float* __restrict__ pinv,
                                                    int* __restrict__ cum,
                                                    int* __restrict__ cnt,
                                                    const float* __restrict__ W0,
                                                    const float* __restrict__ W1,
                                                    const float* __restrict__ W2,
                                                    _Float16* __restrict__ img) {
  __shared__ float red[4];
  if (blockIdx.x < 3) {
    const float* p = (blockIdx.x == 0) ? p0 : (blockIdx.x == 1 ? p1 : p2);
    float s = p[threadIdx.x] * p[threadIdx.x];
    #pragma unroll
    for (int off = 32; off > 0; off >>= 1) s += __shfl_down(s, off);
    int lane = threadIdx.x & 63, wid = threadIdx.x >> 6;
    if (lane == 0) red[wid] = s;
    __syncthreads();
    if (threadIdx.x == 0)
      pinv[blockIdx.x] = 1.0f / sqrtf(red[0] + red[1] + red[2] + red[3]);
  } else if (blockIdx.x < 3 + NODES0 / 256) {
    int v = (blockIdx.x - 3) * 256 + threadIdx.x;
    if (v < NODES0) { cum[v] = v; cnt[v] = 0; }
  } else {
    int wb = blockIdx.x - (3 + NODES0 / 256);
    int l = wb >> 4;
    const float* W = (l == 0) ? W0 : (l == 1 ? W1 : W2);
    int bn = (wb >> 3) & 1, kt = wb & 7;
    int t = threadIdx.x;
    int n = t & 127, kh = t >> 7;
    int k0 = kt * 32 + kh * 16;
    _Float16* row = img + (size_t)l * 16 * TILEHW + ((size_t)(bn * 8 + kt) * 128 + n) * TSTRIDE;
    #pragma unroll
    for (int s = 0; s < 2; ++s) {
      v8h hv, lv;
      #pragma unroll
      for (int j = 0; j < 8; ++j) {
        float a = W[(size_t)(k0 + s * 8 + j) * 256 + bn * 128 + n];
        _Float16 h = (_Float16)a;
        hv[j] = h;
        lv[j] = (_Float16)(a - (float)h);
      }
      *(v8h*)&row[kh * 16 + s * 8] = hv;
      *(v8h*)&row[32 + kh * 16 + s * 8] = lv;
    }
  }
}

// ---------------- layer-0 CSR build (once) ----------------
__global__ void count0_kernel(const int* __restrict__ edst, int* __restrict__ cnt) {
  int e = blockIdx.x * 256 + threadIdx.x;
  if (e < E_) atomicAdd(&cnt[edst[e]], 1);
}

__global__ __launch_bounds__(256) void scan1_kernel(const int* __restrict__ cnt,
                                                    int* __restrict__ row0,
                                                    int* __restrict__ bsum,
                                                    float* __restrict__ dis,
                                                    int* __restrict__ cursor, int n) {
  __shared__ int sdata[256];
  int base = blockIdx.x * 1024;
  int t = threadIdx.x;
  int v[4]; int s = 0;
  #pragma unroll
  for (int i = 0; i < 4; ++i) {
    int idx = base + t * 4 + i;
    v[i] = (idx < n) ? cnt[idx] : 0;
    s += v[i];
    if (idx < n) {
      dis[idx] = 1.0f / sqrtf((float)v[i] + 1.0f);
      cursor[idx] = 0;
    }
  }
  sdata[t] = s;
  __syncthreads();
  for (int off = 1; off < 256; off <<= 1) {
    int x = (t >= off) ? sdata[t - off] : 0;
    __syncthreads();
    sdata[t] += x;
    __syncthreads();
  }
  int excl = sdata[t] - s;
  if (t == 255) bsum[blockIdx.x] = sdata[255];
  #pragma unroll
  for (int i = 0; i < 4; ++i) {
    int idx = base + t * 4 + i;
    if (idx < n) { row0[idx] = excl; excl += v[i]; }
  }
}

__global__ __launch_bounds__(256) void scan2_kernel(int* __restrict__ bsum,
                                                    int* __restrict__ row0, int nb, int n) {
  __shared__ int sdata[256];
  int t = threadIdx.x;
  int v = (t < nb) ? bsum[t] : 0;
  sdata[t] = v;
  __syncthreads();
  for (int off = 1; off < 256; off <<= 1) {
    int x = (t >= off) ? sdata[t - off] : 0;
    __syncthreads();
    sdata[t] += x;
    __syncthreads();
  }
  if (t < nb) bsum[t] = sdata[t] - v;
  if (t == 255) row0[n] = sdata[255];
}

// scatter pairs + emit layer-0 per-node ranges rows[v]={rs,re}
__global__ void fill0_kernel(const int* __restrict__ esrc, const int* __restrict__ edst,
                             const int* __restrict__ row0, const int* __restrict__ bsum,
                             int* __restrict__ cursor, const float* __restrict__ dis,
                             int* __restrict__ csr0, int* __restrict__ csr_dst,
                             int2* __restrict__ pair0, int2* __restrict__ rows) {
  int e = blockIdx.x * 256 + threadIdx.x;
  if (e >= E_) return;
  if (e < NODES0) {
    int rs = row0[e] + bsum[e >> 10];
    int e1 = e + 1;
    int re = (e1 < NODES0) ? row0[e1] + bsum[e1 >> 10] : row0[NODES0];
    rows[e] = make_int2(rs, re);
  }
  int d = edst[e], s = esrc[e];
  int pos = atomicAdd(&cursor[d], 1);
  int idx = row0[d] + bsum[d >> 10] + pos;
  csr0[idx] = s;
  csr_dst[idx] = d;
  pair0[idx] = make_int2(s, __float_as_int(dis[s] * dis[d]));
}

// ---------------- f16x3 MFMA GEMM with perm-gather + sorted-score scale (XCD-aligned) ----------------
__global__ __launch_bounds__(256) void gemm_f16x3_kernel(const float* __restrict__ A,
                                                         const int* __restrict__ perm,
                                                         const float* __restrict__ sscore,
                                                         const _Float16* __restrict__ Wimg,
                                                         float* __restrict__ C) {
  __shared__ _Float16 As[TILEHW];
  __shared__ _Float16 Ws[TILEHW];
  const int tid = threadIdx.x;
  const int flat = xcd_swizzle(blockIdx.x, gridDim.x);
  const int bm = flat >> 1;
  const int bn = flat & 1;
  const int lane = tid & 63, wid = tid >> 6;
  const int wm = wid >> 1, wn = wid & 1;
  const int l15 = lane & 15, kg = lane >> 4;

  v4f acc[4][4];
  #pragma unroll
  for (int i = 0; i < 4; ++i)
    #pragma unroll
    for (int j = 0; j < 4; ++j) acc[i][j] = (v4f){0.f, 0.f, 0.f, 0.f};

  int arow[4], acc4[4];
  const float* aptr[4];
  float ascale[4];
  #pragma unroll
  for (int i = 0; i < 4; ++i) {
    int c = tid + 256 * i;
    arow[i] = c >> 3;
    acc4[i] = c & 7;
    int R = bm * 128 + arow[i];
    int pr = perm ? perm[R] : R;
    ascale[i] = perm ? sscore[R] : 1.0f;
    aptr[i] = A + (size_t)pr * 256 + acc4[i] * 4;
  }
  const _Float16* wtile0 = Wimg + (size_t)bn * 8 * TILEHW;

  float4 pa[4];
  #pragma unroll
  for (int i = 0; i < 4; ++i) pa[i] = *(const float4*)(aptr[i] + 0);

  for (int kt = 0; kt < 8; ++kt) {
    {
      const _Float16* wt = wtile0 + (size_t)kt * TILEHW;
      for (int cb = wid; cb < 18; cb += 4)
        async_copy16(&Ws[cb * 512], wt + (size_t)cb * 512 + lane * 8);
    }
    #pragma unroll
    for (int i = 0; i < 4; ++i) {
      float av[4] = {pa[i].x * ascale[i], pa[i].y * ascale[i],
                     pa[i].z * ascale[i], pa[i].w * ascale[i]};
      v4h hv, lv;
      #pragma unroll
      for (int j = 0; j < 4; ++j) {
        _Float16 h = (_Float16)av[j];
        hv[j] = h;
        lv[j] = (_Float16)(av[j] - (float)h);
      }
      _Float16* dst = &As[arow[i] * TSTRIDE + acc4[i] * 4];
      *(v4h*)(dst) = hv;
      *(v4h*)(dst + 32) = lv;
    }
    __syncthreads();

    if (kt < 7) {
      #pragma unroll
      for (int i = 0; i < 4; ++i)
        pa[i] = *(const float4*)(aptr[i] + (kt + 1) * 32);
    }

    v8h ah[4], bh[4], al[4], bl[4];
    #pragma unroll
    for (int i = 0; i < 4; ++i)
      ah[i] = *(const v8h*)&As[(wm * 64 + i * 16 + l15) * TSTRIDE + kg * 8];
    #pragma unroll
    for (int j = 0; j < 4; ++j)
      bh[j] = *(const v8h*)&Ws[(wn * 64 + j * 16 + l15) * TSTRIDE + kg * 8];
    #pragma unroll
    for (int i = 0; i < 4; ++i)
      #pragma unroll
      for (int j = 0; j < 4; ++j)
        acc[i][j] = __builtin_amdgcn_mfma_f32_16x16x32_f16(ah[i], bh[j], acc[i][j], 0, 0, 0);
    #pragma unroll
    for (int i = 0; i < 4; ++i)
      al[i] = *(const v8h*)&As[(wm * 64 + i * 16 + l15) * TSTRIDE + 32 + kg * 8];
    #pragma unroll
    for (int i = 0; i < 4; ++i)
      #pragma unroll
      for (int j = 0; j < 4; ++j)
        acc[i][j] = __builtin_amdgcn_mfma_f32_16x16x32_f16(al[i], bh[j], acc[i][j], 0, 0, 0);
    #pragma unroll
    for (int j = 0; j < 4; ++j)
      bl[j] = *(const v8h*)&Ws[(wn * 64 + j * 16 + l15) * TSTRIDE + 32 + kg * 8];
    #pragma unroll
    for (int i = 0; i < 4; ++i)
      #pragma unroll
      for (int j = 0; j < 4; ++j)
        acc[i][j] = __builtin_amdgcn_mfma_f32_16x16x32_f16(ah[i], bl[j], acc[i][j], 0, 0, 0);
    __syncthreads();
  }

  #pragma unroll
  for (int i = 0; i < 4; ++i) {
    #pragma unroll
    for (int j = 0; j < 4; ++j) {
      #pragma unroll
      for (int r = 0; r < 4; ++r) {
        int row = bm * 128 + wm * 64 + i * 16 + kg * 4 + r;
        int col = bn * 128 + wn * 64 + j * 16 + l15;
        C[(size_t)row * 256 + col] = acc[i][j][r];
      }
    }
  }
}

// ---------------- aggregate + bias + relu, fused tanh-score (4-wave blocks, NT output stores) ----------------
__global__ __launch_bounds__(256) void agg_score_kernel(
    const float4* __restrict__ hlin4, const float* __restrict__ dis,
    const float4* __restrict__ bias4,
    const int2* __restrict__ rows,
    const int2* __restrict__ edge,
    const float4* __restrict__ p4, const float* __restrict__ pinvp,
    float* __restrict__ hout, float* __restrict__ score) {
  int blk = xcd_swizzle(blockIdx.x, gridDim.x);
  int wave = threadIdx.x >> 6, lane = threadIdx.x & 63;
  int v = blk * 4 + wave;
  int2 rr = rows[v];
  float dv = dis[v];
  float self = dv * dv;
  float4 h = hlin4[(size_t)v * 64 + lane];
  float4 acc = make_float4(h.x * self, h.y * self, h.z * self, h.w * self);
  int j = rr.x, re = rr.y;
  for (; j + 8 <= re; j += 8) {
    int s[8]; float c[8]; float4 hh[8];
    #pragma unroll
    for (int u = 0; u < 8; ++u) {
      int2 e = edge[j + u];
      s[u] = e.x; c[u] = __int_as_float(e.y);
    }
    #pragma unroll
    for (int u = 0; u < 8; ++u) hh[u] = hlin4[(size_t)s[u] * 64 + lane];
    #pragma unroll
    for (int u = 0; u < 8; ++u) acc = f4fma(hh[u], c[u], acc);
  }
  if (j + 4 <= re) {
    int s[4]; float c[4]; float4 hh[4];
    #pragma unroll
    for (int u = 0; u < 4; ++u) {
      int2 e = edge[j + u];
      s[u] = e.x; c[u] = __int_as_float(e.y);
    }
    #pragma unroll
    for (int u = 0; u < 4; ++u) hh[u] = hlin4[(size_t)s[u] * 64 + lane];
    #pragma unroll
    for (int u = 0; u < 4; ++u) acc = f4fma(hh[u], c[u], acc);
    j += 4;
  }
  for (; j < re; ++j) {
    int2 e = edge[j];
    acc = f4fma(hlin4[(size_t)e.x * 64 + lane], __int_as_float(e.y), acc);
  }
  float4 b = bias4[lane];
  acc.x = fmaxf(acc.x + b.x, 0.0f); acc.y = fmaxf(acc.y + b.y, 0.0f);
  acc.z = fmaxf(acc.z + b.z, 0.0f); acc.w = fmaxf(acc.w + b.w, 0.0f);
  v4f accv = (v4f){acc.x, acc.y, acc.z, acc.w};
  __builtin_nontemporal_store(accv, (v4f*)(hout + (size_t)v * 256 + lane * 4));
  float4 pv = p4[lane];
  float s = acc.x * pv.x + acc.y * pv.y + acc.z * pv.z + acc.w * pv.w;
  #pragma unroll
  for (int off = 32; off > 0; off >>= 1) s += __shfl_down(s, off);
  if (lane == 0) __builtin_nontemporal_store(tanhf(s * pinvp[0]), &score[v]);
}

// ---------------- fused top-k + cum update + NEXT-LAYER deg/rows/remap + attention pool ----------------
__global__ __launch_bounds__(512) void topk_pool_kernel(
    const float* __restrict__ score, int n, int k,
    int* __restrict__ cum, int* __restrict__ perm, float* __restrict__ sscore,
    const float4* __restrict__ h4, const float4* __restrict__ attw4,
    const float* __restrict__ attb, float* __restrict__ out, int add,
    int do_next,
    const int* __restrict__ row0, const int* __restrict__ bsum,
    const int* __restrict__ csr0, const int* __restrict__ csr_dst,
    float* __restrict__ dis, int2* __restrict__ rows, int2* __restrict__ pair_l) {
  __shared__ float key[512];
  __shared__ int kid[512];
  __shared__ int newmap[512];
  __shared__ float disl[512];
  __shared__ float wmax[8], wsum[8];
  __shared__ float4 waccs[8][64];
  int g = xcd_swizzle(blockIdx.x, gridDim.x);
  int t = threadIdx.x;

  key[t] = (t < n) ? score[(size_t)g * n + t] : -INFINITY;
  kid[t] = t;
  if (t < n) newmap[t] = -1;
  __syncthreads();
  for (int kk = 2; kk <= 512; kk <<= 1) {
    for (int j = kk >> 1; j > 0; j >>= 1) {
      int i = t, ixj = i ^ j;
      if (ixj > i) {
        float ka = key[i]; int ia = kid[i];
        float kb = key[ixj]; int ib = kid[ixj];
        bool b_first = (kb > ka) || (kb == ka && ib < ia);
        bool sw = ((i & kk) == 0) ? b_first : !b_first;
        if (sw) { key[i] = kb; kid[i] = ib; key[ixj] = ka; kid[ixj] = ia; }
      }
      __syncthreads();
    }
  }
  if (t < k) {
    int local = kid[t];
    perm[g * k + t] = g * n + local;
    newmap[local] = g * k + t;
    sscore[g * k + t] = key[t];
  }
  __syncthreads();
  int vo = g * N0_ + t;
  int c0 = cum[vo];
  if (c0 >= 0) cum[vo] = newmap[c0 - g * n];
  __syncthreads();

  if (do_next) {
    {
      int o = g * N0_ + t;
      int nc = cum[o];
      if (nc >= 0) {
        int rs = row0[o] + bsum[o >> 10];
        int o1 = o + 1;
        int re = (o1 < NODES0) ? row0[o1] + bsum[o1 >> 10] : row0[NODES0];
        int c = 0;
        for (int j = rs; j < re; ++j) c += (cum[csr0[j]] >= 0) ? 1 : 0;
        float dv = rsqrtf((float)c + 1.0f);
        disl[nc - g * k] = dv;
        dis[nc] = dv;
        rows[nc] = make_int2(rs, re);
      }
    }
    __syncthreads();
    int slo = row0[g * N0_] + bsum[(g * N0_) >> 10];
    int shi = (g < G_ - 1) ? row0[(g + 1) * N0_] + bsum[((g + 1) * N0_) >> 10] : row0[NODES0];
    for (int j = slo + t; j < shi; j += 512) {
      int md = cum[csr_dst[j]];
      if (md < 0) continue;
      int ms = cum[csr0[j]];
      float cf = (ms >= 0) ? disl[ms - g * k] * disl[md - g * k] : 0.0f;
      pair_l[j] = make_int2((ms >= 0) ? ms : md, __float_as_int(cf));
    }
  }

  // ---- pool phase (kid/key resident in LDS) ----
  int wave = t >> 6, lane = t & 63;
  float4 aw = attw4[lane];
  float ab = attb[0];
  float m = -INFINITY, ssum = 0.0f;
  float4 acc = make_float4(0.f, 0.f, 0.f, 0.f);
  for (int i = wave; i < k; i += 8) {
    int node = g * n + kid[i];
    float sc = key[i];
    float4 hv = h4[(size_t)node * 64 + lane];
    float4 val = make_float4(hv.x * sc, hv.y * sc, hv.z * sc, hv.w * sc);
    float gd = val.x * aw.x + val.y * aw.y + val.z * aw.z + val.w * aw.w;
    #pragma unroll
    for (int off = 32; off > 0; off >>= 1) gd += __shfl_xor(gd, off);
    float gi = gd + ab;
    float mnew = fmaxf(m, gi);
    float f = __expf(m - mnew);
    float e = __expf(gi - mnew);
    acc.x = acc.x * f + val.x * e; acc.y = acc.y * f + val.y * e;
    acc.z = acc.z * f + val.z * e; acc.w = acc.w * f + val.w * e;
    ssum = ssum * f + e;
    m = mnew;
  }
  if (lane == 0) { wmax[wave] = m; wsum[wave] = ssum; }
  waccs[wave][lane] = acc;
  __syncthreads();
  if (wave == 0) {
    float mstar = wmax[0];
    #pragma unroll
    for (int w = 1; w < 8; ++w) mstar = fmaxf(mstar, wmax[w]);
    float stot = 0.0f;
    float4 a = make_float4(0.f, 0.f, 0.f, 0.f);
    #pragma unroll
    for (int w = 0; w < 8; ++w) {
      float sc = __expf(wmax[w] - mstar);
      stot += wsum[w] * sc;
      float4 wa = waccs[w][lane];
      a.x += wa.x * sc; a.y += wa.y * sc; a.z += wa.z * sc; a.w += wa.w * sc;
    }
    float inv = 1.0f / stot;
    a.x *= inv; a.y *= inv; a.z *= inv; a.w *= inv;
    float4* o4 = (float4*)out + (size_t)g * 64 + lane;
    if (add) {
      float4 prev = *o4;
      a.x += prev.x; a.y += prev.y; a.z += prev.z; a.w += prev.w;
    }
    *o4 = a;
  }
}

// ---------------- host orchestration ----------------
extern "C" void kernel_launch(void* const* d_in, const int* in_sizes, int n_in,
                              void* d_out, int out_size, void* d_ws, size_t ws_size,
                              hipStream_t stream) {
  const float* x    = (const float*)d_in[0];
  const int*   esrc = (const int*)d_in[1];
  const int*   edst = (const int*)d_in[2];
  const float* Wl[3] = {(const float*)d_in[3], (const float*)d_in[5], (const float*)d_in[7]};
  const float* bl[3] = {(const float*)d_in[4], (const float*)d_in[6], (const float*)d_in[8]};
  const float* pl[3] = {(const float*)d_in[9], (const float*)d_in[10], (const float*)d_in[11]};
  const float* attw = (const float*)d_in[12];
  const float* attb = (const float*)d_in[13];
  float* out = (float*)d_out;

  char* w = (char*)d_ws;
  auto carve = [&](size_t bytes) { char* p = w; w += (bytes + 255) & ~(size_t)255; return p; };
  float* bufA    = (float*)carve((size_t)NODES0 * H_ * 4);   // hlin
  float* bufB    = (float*)carve((size_t)NODES0 * H_ * 4);   // hbuf
  int*   csr0    = (int*)  carve((size_t)E_ * 4);
  int*   csr_dst = (int*)  carve((size_t)E_ * 4);
  int2*  pair0   = (int2*) carve((size_t)E_ * 8);
  int2*  pair_l  = (int2*) carve((size_t)E_ * 8);
  int*   cnt     = (int*)  carve((size_t)NODES0 * 4);
  int*   row0    = (int*)  carve((size_t)(NODES0 + 1) * 4);
  int*   cursor  = (int*)  carve((size_t)NODES0 * 4);
  float* dis     = (float*)carve((size_t)NODES0 * 4);
  float* score   = (float*)carve((size_t)NODES0 * 4);
  float* sscore  = (float*)carve((size_t)NODES0 * 4);
  int*   cum_map = (int*)  carve((size_t)NODES0 * 4);
  int*   perm    = (int*)  carve((size_t)NODES0 * 4);
  int2*  rows    = (int2*) carve((size_t)NODES0 * 8);
  int*   bsum    = (int*)  carve(256 * 4);
  float* pinv    = (float*)carve(16);
  _Float16* Wimg = (_Float16*)carve((size_t)3 * 16 * TILEHW * 2);  // 864 KB
  (void)ws_size; (void)in_sizes; (void)n_in; (void)out_size;

  setup_kernel<<<3 + NODES0 / 256 + 48, 256, 0, stream>>>(
      pl[0], pl[1], pl[2], pinv, cum_map, cnt, Wl[0], Wl[1], Wl[2], Wimg);

  count0_kernel<<<E_ / 256, 256, 0, stream>>>(edst, cnt);
  int nb0 = (NODES0 + 1023) / 1024;
  scan1_kernel<<<nb0, 256, 0, stream>>>(cnt, row0, bsum, dis, cursor, NODES0);
  scan2_kernel<<<1, 256, 0, stream>>>(bsum, row0, nb0, NODES0);
  fill0_kernel<<<E_ / 256, 256, 0, stream>>>(esrc, edst, row0, bsum, cursor, dis,
                                             csr0, csr_dst, pair0, rows);

  int n_cur = N0_;
  for (int l = 0; l < 3; ++l) {
    int nodes = G_ * n_cur;

    gemm_f16x3_kernel<<<(nodes / 128) * 2, 256, 0, stream>>>(
        (l == 0) ? x : bufB, (l == 0) ? nullptr : perm, sscore,
        Wimg + (size_t)l * 16 * TILEHW, bufA);

    agg_score_kernel<<<nodes / 4, 256, 0, stream>>>(
        (const float4*)bufA, dis, (const float4*)bl[l], rows,
        (l == 0) ? pair0 : pair_l,
        (const float4*)pl[l], pinv + l, bufB, score);

    int kk = (int)std::ceil(0.8 * (double)n_cur);
    topk_pool_kernel<<<G_, 512, 0, stream>>>(
        score, n_cur, kk, cum_map, perm, sscore,
        (const float4*)bufB, (const float4*)attw, attb, out, l > 0 ? 1 : 0,
        (l < 2) ? 1 : 0, row0, bsum, csr0, csr_dst, dis, rows, pair_l);

    n_cur = kk;
  }
}

// Round 19
// 375.637 us; speedup vs baseline: 1.0711x; 1.0711x over previous
//
#include <hip/hip_runtime.h>
#include <cmath>

#define G_ 128
#define N0_ 512
#define H_ 256
#define E_ 524288
#define NODES0 (G_*N0_)

typedef _Float16 v8h __attribute__((ext_vector_type(8)));
typedef _Float16 v4h __attribute__((ext_vector_type(4)));
typedef float v4f __attribute__((ext_vector_type(4)));

#define TSTRIDE 72           // halfwords per tile row: 32 hi + 32 lo + 8 pad
#define TILEHW (128*TSTRIDE) // 9216 halfwords = 18432 B per tile

__device__ __forceinline__ void async_copy16(void* lds, const void* g) {
  __builtin_amdgcn_global_load_lds(
      (const __attribute__((address_space(1))) void*)g,
      (__attribute__((address_space(3))) void*)lds, 16, 0, 0);
}

// Bijective XCD swizzle (m204 form).
__device__ __forceinline__ int xcd_swizzle(int orig, int nb) {
  int q = nb >> 3, r = nb & 7;
  int xcd = orig & 7, local = orig >> 3;
  int off = (xcd < r) ? xcd * (q + 1) : r * (q + 1) + (xcd - r) * q;
  return off + local;
}

__device__ __forceinline__ float4 f4fma(float4 a, float s, float4 acc) {
  acc.x = fmaf(a.x, s, acc.x); acc.y = fmaf(a.y, s, acc.y);
  acc.z = fmaf(a.z, s, acc.z); acc.w = fmaf(a.w, s, acc.w);
  return acc;
}

// ---------------- setup: pnorm (0-2) + init (3..130) + wconv (131..178) ----------------
__global__ __launch_bounds__(256) void setup_kernel(const float* __restrict__ p0,
                                                    const float* __restrict__ p1,
                                                    const float* __restrict__ p2,
                                                    float* __restrict__ pinv,
                                                    int* __restrict__ cum,
                                                    int* __restrict__ cnt,
                                                    const float* __restrict__ W0,
                                                    const float* __restrict__ W1,
                                                    const float* __restrict__ W2,
                                                    _Float16* __restrict__ img) {
  __shared__ float red[4];
  if (blockIdx.x < 3) {
    const float* p = (blockIdx.x == 0) ? p0 : (blockIdx.x == 1 ? p1 : p2);
    float s = p[threadIdx.x] * p[threadIdx.x];
    #pragma unroll
    for (int off = 32; off > 0; off >>= 1) s += __shfl_down(s, off);
    int lane = threadIdx.x & 63, wid = threadIdx.x >> 6;
    if (lane == 0) red[wid] = s;
    __syncthreads();
    if (threadIdx.x == 0)
      pinv[blockIdx.x] = 1.0f / sqrtf(red[0] + red[1] + red[2] + red[3]);
  } else if (blockIdx.x < 3 + NODES0 / 256) {
    int v = (blockIdx.x - 3) * 256 + threadIdx.x;
    if (v < NODES0) { cum[v] = v; cnt[v] = 0; }
  } else {
    int wb = blockIdx.x - (3 + NODES0 / 256);
    int l = wb >> 4;
    const float* W = (l == 0) ? W0 : (l == 1 ? W1 : W2);
    int bn = (wb >> 3) & 1, kt = wb & 7;
    int t = threadIdx.x;
    int n = t & 127, kh = t >> 7;
    int k0 = kt * 32 + kh * 16;
    _Float16* row = img + (size_t)l * 16 * TILEHW + ((size_t)(bn * 8 + kt) * 128 + n) * TSTRIDE;
    #pragma unroll
    for (int s = 0; s < 2; ++s) {
      v8h hv, lv;
      #pragma unroll
      for (int j = 0; j < 8; ++j) {
        float a = W[(size_t)(k0 + s * 8 + j) * 256 + bn * 128 + n];
        _Float16 h = (_Float16)a;
        hv[j] = h;
        lv[j] = (_Float16)(a - (float)h);
      }
      *(v8h*)&row[kh * 16 + s * 8] = hv;
      *(v8h*)&row[32 + kh * 16 + s * 8] = lv;
    }
  }
}

// ---------------- layer-0 CSR build (once) ----------------
__global__ void count0_kernel(const int* __restrict__ edst, int* __restrict__ cnt) {
  int e = blockIdx.x * 256 + threadIdx.x;
  if (e < E_) atomicAdd(&cnt[edst[e]], 1);
}

__global__ __launch_bounds__(256) void scan1_kernel(const int* __restrict__ cnt,
                                                    int* __restrict__ row0,
                                                    int* __restrict__ bsum,
                                                    float* __restrict__ dis,
                                                    int* __restrict__ cursor, int n) {
  __shared__ int sdata[256];
  int base = blockIdx.x * 1024;
  int t = threadIdx.x;
  int v[4]; int s = 0;
  #pragma unroll
  for (int i = 0; i < 4; ++i) {
    int idx = base + t * 4 + i;
    v[i] = (idx < n) ? cnt[idx] : 0;
    s += v[i];
    if (idx < n) {
      dis[idx] = 1.0f / sqrtf((float)v[i] + 1.0f);
      cursor[idx] = 0;
    }
  }
  sdata[t] = s;
  __syncthreads();
  for (int off = 1; off < 256; off <<= 1) {
    int x = (t >= off) ? sdata[t - off] : 0;
    __syncthreads();
    sdata[t] += x;
    __syncthreads();
  }
  int excl = sdata[t] - s;
  if (t == 255) bsum[blockIdx.x] = sdata[255];
  #pragma unroll
  for (int i = 0; i < 4; ++i) {
    int idx = base + t * 4 + i;
    if (idx < n) { row0[idx] = excl; excl += v[i]; }
  }
}

__global__ __launch_bounds__(256) void scan2_kernel(int* __restrict__ bsum,
                                                    int* __restrict__ row0, int nb, int n) {
  __shared__ int sdata[256];
  int t = threadIdx.x;
  int v = (t < nb) ? bsum[t] : 0;
  sdata[t] = v;
  __syncthreads();
  for (int off = 1; off < 256; off <<= 1) {
    int x = (t >= off) ? sdata[t - off] : 0;
    __syncthreads();
    sdata[t] += x;
    __syncthreads();
  }
  if (t < nb) bsum[t] = sdata[t] - v;
  if (t == 255) row0[n] = sdata[255];
}

// scatter pairs + emit layer-0 per-node ranges rows[v]={rs,re}
__global__ void fill0_kernel(const int* __restrict__ esrc, const int* __restrict__ edst,
                             const int* __restrict__ row0, const int* __restrict__ bsum,
                             int* __restrict__ cursor, const float* __restrict__ dis,
                             int* __restrict__ csr0, int* __restrict__ csr_dst,
                             int2* __restrict__ pair0, int2* __restrict__ rows) {
  int e = blockIdx.x * 256 + threadIdx.x;
  if (e >= E_) return;
  if (e < NODES0) {
    int rs = row0[e] + bsum[e >> 10];
    int e1 = e + 1;
    int re = (e1 < NODES0) ? row0[e1] + bsum[e1 >> 10] : row0[NODES0];
    rows[e] = make_int2(rs, re);
  }
  int d = edst[e], s = esrc[e];
  int pos = atomicAdd(&cursor[d], 1);
  int idx = row0[d] + bsum[d >> 10] + pos;
  csr0[idx] = s;
  csr_dst[idx] = d;
  pair0[idx] = make_int2(s, __float_as_int(dis[s] * dis[d]));
}

// ---------------- f16x3 MFMA GEMM with perm-gather + sorted-score scale (XCD-aligned) ----------------
__global__ __launch_bounds__(256) void gemm_f16x3_kernel(const float* __restrict__ A,
                                                         const int* __restrict__ perm,
                                                         const float* __restrict__ sscore,
                                                         const _Float16* __restrict__ Wimg,
                                                         float* __restrict__ C) {
  __shared__ _Float16 As[TILEHW];
  __shared__ _Float16 Ws[TILEHW];
  const int tid = threadIdx.x;
  const int flat = xcd_swizzle(blockIdx.x, gridDim.x);
  const int bm = flat >> 1;
  const int bn = flat & 1;
  const int lane = tid & 63, wid = tid >> 6;
  const int wm = wid >> 1, wn = wid & 1;
  const int l15 = lane & 15, kg = lane >> 4;

  v4f acc[4][4];
  #pragma unroll
  for (int i = 0; i < 4; ++i)
    #pragma unroll
    for (int j = 0; j < 4; ++j) acc[i][j] = (v4f){0.f, 0.f, 0.f, 0.f};

  int arow[4], acc4[4];
  const float* aptr[4];
  float ascale[4];
  #pragma unroll
  for (int i = 0; i < 4; ++i) {
    int c = tid + 256 * i;
    arow[i] = c >> 3;
    acc4[i] = c & 7;
    int R = bm * 128 + arow[i];
    int pr = perm ? perm[R] : R;
    ascale[i] = perm ? sscore[R] : 1.0f;
    aptr[i] = A + (size_t)pr * 256 + acc4[i] * 4;
  }
  const _Float16* wtile0 = Wimg + (size_t)bn * 8 * TILEHW;

  float4 pa[4];
  #pragma unroll
  for (int i = 0; i < 4; ++i) pa[i] = *(const float4*)(aptr[i] + 0);

  for (int kt = 0; kt < 8; ++kt) {
    {
      const _Float16* wt = wtile0 + (size_t)kt * TILEHW;
      for (int cb = wid; cb < 18; cb += 4)
        async_copy16(&Ws[cb * 512], wt + (size_t)cb * 512 + lane * 8);
    }
    #pragma unroll
    for (int i = 0; i < 4; ++i) {
      float av[4] = {pa[i].x * ascale[i], pa[i].y * ascale[i],
                     pa[i].z * ascale[i], pa[i].w * ascale[i]};
      v4h hv, lv;
      #pragma unroll
      for (int j = 0; j < 4; ++j) {
        _Float16 h = (_Float16)av[j];
        hv[j] = h;
        lv[j] = (_Float16)(av[j] - (float)h);
      }
      _Float16* dst = &As[arow[i] * TSTRIDE + acc4[i] * 4];
      *(v4h*)(dst) = hv;
      *(v4h*)(dst + 32) = lv;
    }
    __syncthreads();

    if (kt < 7) {
      #pragma unroll
      for (int i = 0; i < 4; ++i)
        pa[i] = *(const float4*)(aptr[i] + (kt + 1) * 32);
    }

    v8h ah[4], bh[4], al[4], bl[4];
    #pragma unroll
    for (int i = 0; i < 4; ++i)
      ah[i] = *(const v8h*)&As[(wm * 64 + i * 16 + l15) * TSTRIDE + kg * 8];
    #pragma unroll
    for (int j = 0; j < 4; ++j)
      bh[j] = *(const v8h*)&Ws[(wn * 64 + j * 16 + l15) * TSTRIDE + kg * 8];
    #pragma unroll
    for (int i = 0; i < 4; ++i)
      #pragma unroll
      for (int j = 0; j < 4; ++j)
        acc[i][j] = __builtin_amdgcn_mfma_f32_16x16x32_f16(ah[i], bh[j], acc[i][j], 0, 0, 0);
    #pragma unroll
    for (int i = 0; i < 4; ++i)
      al[i] = *(const v8h*)&As[(wm * 64 + i * 16 + l15) * TSTRIDE + 32 + kg * 8];
    #pragma unroll
    for (int i = 0; i < 4; ++i)
      #pragma unroll
      for (int j = 0; j < 4; ++j)
        acc[i][j] = __builtin_amdgcn_mfma_f32_16x16x32_f16(al[i], bh[j], acc[i][j], 0, 0, 0);
    #pragma unroll
    for (int j = 0; j < 4; ++j)
      bl[j] = *(const v8h*)&Ws[(wn * 64 + j * 16 + l15) * TSTRIDE + 32 + kg * 8];
    #pragma unroll
    for (int i = 0; i < 4; ++i)
      #pragma unroll
      for (int j = 0; j < 4; ++j)
        acc[i][j] = __builtin_amdgcn_mfma_f32_16x16x32_f16(ah[i], bl[j], acc[i][j], 0, 0, 0);
    __syncthreads();
  }

  #pragma unroll
  for (int i = 0; i < 4; ++i) {
    #pragma unroll
    for (int j = 0; j < 4; ++j) {
      #pragma unroll
      for (int r = 0; r < 4; ++r) {
        int row = bm * 128 + wm * 64 + i * 16 + kg * 4 + r;
        int col = bn * 128 + wn * 64 + j * 16 + l15;
        C[(size_t)row * 256 + col] = acc[i][j][r];
      }
    }
  }
}

// ---------------- aggregate + bias + relu, fused tanh-score (4-wave blocks, plain stores) ----------------
__global__ __launch_bounds__(256) void agg_score_kernel(
    const float4* __restrict__ hlin4, const float* __restrict__ dis,
    const float4* __restrict__ bias4,
    const int2* __restrict__ rows,
    const int2* __restrict__ edge,
    const float4* __restrict__ p4, const float* __restrict__ pinvp,
    float4* __restrict__ hout4, float* __restrict__ score) {
  int blk = xcd_swizzle(blockIdx.x, gridDim.x);
  int wave = threadIdx.x >> 6, lane = threadIdx.x & 63;
  int v = blk * 4 + wave;
  int2 rr = rows[v];
  float dv = dis[v];
  float self = dv * dv;
  float4 h = hlin4[(size_t)v * 64 + lane];
  float4 acc = make_float4(h.x * self, h.y * self, h.z * self, h.w * self);
  int j = rr.x, re = rr.y;
  for (; j + 8 <= re; j += 8) {
    int s[8]; float c[8]; float4 hh[8];
    #pragma unroll
    for (int u = 0; u < 8; ++u) {
      int2 e = edge[j + u];
      s[u] = e.x; c[u] = __int_as_float(e.y);
    }
    #pragma unroll
    for (int u = 0; u < 8; ++u) hh[u] = hlin4[(size_t)s[u] * 64 + lane];
    #pragma unroll
    for (int u = 0; u < 8; ++u) acc = f4fma(hh[u], c[u], acc);
  }
  if (j + 4 <= re) {
    int s[4]; float c[4]; float4 hh[4];
    #pragma unroll
    for (int u = 0; u < 4; ++u) {
      int2 e = edge[j + u];
      s[u] = e.x; c[u] = __int_as_float(e.y);
    }
    #pragma unroll
    for (int u = 0; u < 4; ++u) hh[u] = hlin4[(size_t)s[u] * 64 + lane];
    #pragma unroll
    for (int u = 0; u < 4; ++u) acc = f4fma(hh[u], c[u], acc);
    j += 4;
  }
  for (; j < re; ++j) {
    int2 e = edge[j];
    acc = f4fma(hlin4[(size_t)e.x * 64 + lane], __int_as_float(e.y), acc);
  }
  float4 b = bias4[lane];
  acc.x = fmaxf(acc.x + b.x, 0.0f); acc.y = fmaxf(acc.y + b.y, 0.0f);
  acc.z = fmaxf(acc.z + b.z, 0.0f); acc.w = fmaxf(acc.w + b.w, 0.0f);
  hout4[(size_t)v * 64 + lane] = acc;
  float4 pv = p4[lane];
  float s = acc.x * pv.x + acc.y * pv.y + acc.z * pv.z + acc.w * pv.w;
  #pragma unroll
  for (int off = 32; off > 0; off >>= 1) s += __shfl_down(s, off);
  if (lane == 0) score[v] = tanhf(s * pinvp[0]);
}

// ---------------- fused top-k + cum update + NEXT-LAYER deg/rows/remap + attention pool ----------------
__global__ __launch_bounds__(512) void topk_pool_kernel(
    const float* __restrict__ score, int n, int k,
    int* __restrict__ cum, int* __restrict__ perm, float* __restrict__ sscore,
    const float4* __restrict__ h4, const float4* __restrict__ attw4,
    const float* __restrict__ attb, float* __restrict__ out, int add,
    int do_next,
    const int* __restrict__ row0, const int* __restrict__ bsum,
    const int* __restrict__ csr0, const int* __restrict__ csr_dst,
    float* __restrict__ dis, int2* __restrict__ rows, int2* __restrict__ pair_l) {
  __shared__ float key[512];
  __shared__ int kid[512];
  __shared__ int newmap[512];
  __shared__ float disl[512];
  __shared__ float wmax[8], wsum[8];
  __shared__ float4 waccs[8][64];
  int g = xcd_swizzle(blockIdx.x, gridDim.x);
  int t = threadIdx.x;

  key[t] = (t < n) ? score[(size_t)g * n + t] : -INFINITY;
  kid[t] = t;
  if (t < n) newmap[t] = -1;
  __syncthreads();
  for (int kk = 2; kk <= 512; kk <<= 1) {
    for (int j = kk >> 1; j > 0; j >>= 1) {
      int i = t, ixj = i ^ j;
      if (ixj > i) {
        float ka = key[i]; int ia = kid[i];
        float kb = key[ixj]; int ib = kid[ixj];
        bool b_first = (kb > ka) || (kb == ka && ib < ia);
        bool sw = ((i & kk) == 0) ? b_first : !b_first;
        if (sw) { key[i] = kb; kid[i] = ib; key[ixj] = ka; kid[ixj] = ia; }
      }
      __syncthreads();
    }
  }
  if (t < k) {
    int local = kid[t];
    perm[g * k + t] = g * n + local;
    newmap[local] = g * k + t;
    sscore[g * k + t] = key[t];
  }
  __syncthreads();
  int vo = g * N0_ + t;
  int c0 = cum[vo];
  if (c0 >= 0) cum[vo] = newmap[c0 - g * n];
  __syncthreads();

  if (do_next) {
    {
      int o = g * N0_ + t;
      int nc = cum[o];
      if (nc >= 0) {
        int rs = row0[o] + bsum[o >> 10];
        int o1 = o + 1;
        int re = (o1 < NODES0) ? row0[o1] + bsum[o1 >> 10] : row0[NODES0];
        int c = 0;
        for (int j = rs; j < re; ++j) c += (cum[csr0[j]] >= 0) ? 1 : 0;
        float dv = rsqrtf((float)c + 1.0f);
        disl[nc - g * k] = dv;
        dis[nc] = dv;
        rows[nc] = make_int2(rs, re);
      }
    }
    __syncthreads();
    int slo = row0[g * N0_] + bsum[(g * N0_) >> 10];
    int shi = (g < G_ - 1) ? row0[(g + 1) * N0_] + bsum[((g + 1) * N0_) >> 10] : row0[NODES0];
    for (int j = slo + t; j < shi; j += 512) {
      int md = cum[csr_dst[j]];
      if (md < 0) continue;
      int ms = cum[csr0[j]];
      float cf = (ms >= 0) ? disl[ms - g * k] * disl[md - g * k] : 0.0f;
      pair_l[j] = make_int2((ms >= 0) ? ms : md, __float_as_int(cf));
    }
  }

  // ---- pool phase (kid/key resident in LDS) ----
  int wave = t >> 6, lane = t & 63;
  float4 aw = attw4[lane];
  float ab = attb[0];
  float m = -INFINITY, ssum = 0.0f;
  float4 acc = make_float4(0.f, 0.f, 0.f, 0.f);
  for (int i = wave; i < k; i += 8) {
    int node = g * n + kid[i];
    float sc = key[i];
    float4 hv = h4[(size_t)node * 64 + lane];
    float4 val = make_float4(hv.x * sc, hv.y * sc, hv.z * sc, hv.w * sc);
    float gd = val.x * aw.x + val.y * aw.y + val.z * aw.z + val.w * aw.w;
    #pragma unroll
    for (int off = 32; off > 0; off >>= 1) gd += __shfl_xor(gd, off);
    float gi = gd + ab;
    float mnew = fmaxf(m, gi);
    float f = __expf(m - mnew);
    float e = __expf(gi - mnew);
    acc.x = acc.x * f + val.x * e; acc.y = acc.y * f + val.y * e;
    acc.z = acc.z * f + val.z * e; acc.w = acc.w * f + val.w * e;
    ssum = ssum * f + e;
    m = mnew;
  }
  if (lane == 0) { wmax[wave] = m; wsum[wave] = ssum; }
  waccs[wave][lane] = acc;
  __syncthreads();
  if (wave == 0) {
    float mstar = wmax[0];
    #pragma unroll
    for (int w = 1; w < 8; ++w) mstar = fmaxf(mstar, wmax[w]);
    float stot = 0.0f;
    float4 a = make_float4(0.f, 0.f, 0.f, 0.f);
    #pragma unroll
    for (int w = 0; w < 8; ++w) {
      float sc = __expf(wmax[w] - mstar);
      stot += wsum[w] * sc;
      float4 wa = waccs[w][lane];
      a.x += wa.x * sc; a.y += wa.y * sc; a.z += wa.z * sc; a.w += wa.w * sc;
    }
    float inv = 1.0f / stot;
    a.x *= inv; a.y *= inv; a.z *= inv; a.w *= inv;
    float4* o4 = (float4*)out + (size_t)g * 64 + lane;
    if (add) {
      float4 prev = *o4;
      a.x += prev.x; a.y += prev.y; a.z += prev.z; a.w += prev.w;
    }
    *o4 = a;
  }
}

// ---------------- host orchestration ----------------
extern "C" void kernel_launch(void* const* d_in, const int* in_sizes, int n_in,
                              void* d_out, int out_size, void* d_ws, size_t ws_size,
                              hipStream_t stream) {
  const float* x    = (const float*)d_in[0];
  const int*   esrc = (const int*)d_in[1];
  const int*   edst = (const int*)d_in[2];
  const float* Wl[3] = {(const float*)d_in[3], (const float*)d_in[5], (const float*)d_in[7]};
  const float* bl[3] = {(const float*)d_in[4], (const float*)d_in[6], (const float*)d_in[8]};
  const float* pl[3] = {(const float*)d_in[9], (const float*)d_in[10], (const float*)d_in[11]};
  const float* attw = (const float*)d_in[12];
  const float* attb = (const float*)d_in[13];
  float* out = (float*)d_out;

  char* w = (char*)d_ws;
  auto carve = [&](size_t bytes) { char* p = w; w += (bytes + 255) & ~(size_t)255; return p; };
  float* bufA    = (float*)carve((size_t)NODES0 * H_ * 4);   // hlin
  float* bufB    = (float*)carve((size_t)NODES0 * H_ * 4);   // hbuf
  int*   csr0    = (int*)  carve((size_t)E_ * 4);
  int*   csr_dst = (int*)  carve((size_t)E_ * 4);
  int2*  pair0   = (int2*) carve((size_t)E_ * 8);
  int2*  pair_l  = (int2*) carve((size_t)E_ * 8);
  int*   cnt     = (int*)  carve((size_t)NODES0 * 4);
  int*   row0    = (int*)  carve((size_t)(NODES0 + 1) * 4);
  int*   cursor  = (int*)  carve((size_t)NODES0 * 4);
  float* dis     = (float*)carve((size_t)NODES0 * 4);
  float* score   = (float*)carve((size_t)NODES0 * 4);
  float* sscore  = (float*)carve((size_t)NODES0 * 4);
  int*   cum_map = (int*)  carve((size_t)NODES0 * 4);
  int*   perm    = (int*)  carve((size_t)NODES0 * 4);
  int2*  rows    = (int2*) carve((size_t)NODES0 * 8);
  int*   bsum    = (int*)  carve(256 * 4);
  float* pinv    = (float*)carve(16);
  _Float16* Wimg = (_Float16*)carve((size_t)3 * 16 * TILEHW * 2);  // 864 KB
  (void)ws_size; (void)in_sizes; (void)n_in; (void)out_size;

  setup_kernel<<<3 + NODES0 / 256 + 48, 256, 0, stream>>>(
      pl[0], pl[1], pl[2], pinv, cum_map, cnt, Wl[0], Wl[1], Wl[2], Wimg);

  count0_kernel<<<E_ / 256, 256, 0, stream>>>(edst, cnt);
  int nb0 = (NODES0 + 1023) / 1024;
  scan1_kernel<<<nb0, 256, 0, stream>>>(cnt, row0, bsum, dis, cursor, NODES0);
  scan2_kernel<<<1, 256, 0, stream>>>(bsum, row0, nb0, NODES0);
  fill0_kernel<<<E_ / 256, 256, 0, stream>>>(esrc, edst, row0, bsum, cursor, dis,
                                             csr0, csr_dst, pair0, rows);

  int n_cur = N0_;
  for (int l = 0; l < 3; ++l) {
    int nodes = G_ * n_cur;

    gemm_f16x3_kernel<<<(nodes / 128) * 2, 256, 0, stream>>>(
        (l == 0) ? x : bufB, (l == 0) ? nullptr : perm, sscore,
        Wimg + (size_t)l * 16 * TILEHW, bufA);

    agg_score_kernel<<<nodes / 4, 256, 0, stream>>>(
        (const float4*)bufA, dis, (const float4*)bl[l], rows,
        (l == 0) ? pair0 : pair_l,
        (const float4*)pl[l], pinv + l, (float4*)bufB, score);

    int kk = (int)std::ceil(0.8 * (double)n_cur);
    topk_pool_kernel<<<G_, 512, 0, stream>>>(
        score, n_cur, kk, cum_map, perm, sscore,
        (const float4*)bufB, (const float4*)attw, attb, out, l > 0 ? 1 : 0,
        (l < 2) ? 1 : 0, row0, bsum, csr0, csr_dst, dis, rows, pair_l);

    n_cur = kk;
  }
}